// Round 1
// baseline (447.450 us; speedup 1.0000x reference)
//
#include <hip/hip_runtime.h>
#include <hip/hip_bf16.h>
#include <math.h>

using bf16 = __hip_bfloat16;
typedef __attribute__((ext_vector_type(8))) short short8v;
typedef __attribute__((ext_vector_type(4))) float f32x4;

#define DEV __device__ __forceinline__

// async global->LDS, 16B per lane. LDS dest must be wave-uniform base (HW adds lane*16).
DEV void load_lds16(const bf16* gsrc, bf16* ldst) {
  __builtin_amdgcn_global_load_lds((const __attribute__((address_space(1))) void*)gsrc,
                                   (__attribute__((address_space(3))) void*)ldst, 16, 0, 0);
}

// ---------------- transpose + fp32->bf16 convert: W[K][N] -> WT[N][K] ----------------
__global__ __launch_bounds__(256) void tconv(const float* __restrict__ W, bf16* __restrict__ WT,
                                             int K, int N) {
  __shared__ float tile[64][65];
  const int n0 = blockIdx.x * 64, k0 = blockIdx.y * 64;
  const int tx = threadIdx.x & 15, ty = threadIdx.x >> 4;
#pragma unroll
  for (int p = 0; p < 4; ++p) {
    int r = p * 16 + ty;
    float4 vv = *(const float4*)&W[(size_t)(k0 + r) * N + n0 + tx * 4];
    tile[r][tx * 4 + 0] = vv.x; tile[r][tx * 4 + 1] = vv.y;
    tile[r][tx * 4 + 2] = vv.z; tile[r][tx * 4 + 3] = vv.w;
  }
  __syncthreads();
#pragma unroll
  for (int p = 0; p < 4; ++p) {
    int n = p * 16 + ty;
    bf16* dst = WT + (size_t)(n0 + n) * K + k0 + tx * 4;
#pragma unroll
    for (int j = 0; j < 4; ++j) dst[j] = __float2bfloat16(tile[tx * 4 + j][n]);
  }
}

// ---------------- LayerNorm: fp32 [rows][1024] -> bf16 ----------------
__global__ __launch_bounds__(256) void ln_kernel(const float* __restrict__ x,
                                                 const float* __restrict__ g,
                                                 const float* __restrict__ b,
                                                 bf16* __restrict__ out) {
  const int row = blockIdx.x, t = threadIdx.x;
  const float4 v = ((const float4*)(x + (size_t)row * 1024))[t];
  float s = v.x + v.y + v.z + v.w;
#pragma unroll
  for (int mm = 1; mm < 64; mm <<= 1) s += __shfl_xor(s, mm);
  __shared__ float r1[4], r2[4];
  if ((t & 63) == 0) r1[t >> 6] = s;
  __syncthreads();
  const float mean = (r1[0] + r1[1] + r1[2] + r1[3]) * (1.0f / 1024.0f);
  const float d0 = v.x - mean, d1 = v.y - mean, d2 = v.z - mean, d3 = v.w - mean;
  float s2 = d0 * d0 + d1 * d1 + d2 * d2 + d3 * d3;
#pragma unroll
  for (int mm = 1; mm < 64; mm <<= 1) s2 += __shfl_xor(s2, mm);
  if ((t & 63) == 0) r2[t >> 6] = s2;
  __syncthreads();
  const float var = (r2[0] + r2[1] + r2[2] + r2[3]) * (1.0f / 1024.0f);
  const float rinv = rsqrtf(var + 1e-5f);
  const int c = t * 4;
  bf16* o = out + (size_t)row * 1024 + c;
  o[0] = __float2bfloat16(d0 * rinv * g[c + 0] + b[c + 0]);
  o[1] = __float2bfloat16(d1 * rinv * g[c + 1] + b[c + 1]);
  o[2] = __float2bfloat16(d2 * rinv * g[c + 2] + b[c + 2]);
  o[3] = __float2bfloat16(d3 * rinv * g[c + 3] + b[c + 3]);
}

// ---------------- GEMM: C[M][N] = A[M][K] * BT[N][K]^T + bias, fused epilogues ----------------
// EPI 0: qkv -> bf16 out with [B,NH,S,HD] remap (3 outputs via blockIdx.z)
// EPI 1: fp32 out = res + acc + bias
// EPI 2: bf16 out = gelu(acc + bias)
template <int EPI>
__global__ __launch_bounds__(256) void gemm128(
    const bf16* __restrict__ A,
    const bf16* __restrict__ B0, const bf16* __restrict__ B1, const bf16* __restrict__ B2,
    const float* __restrict__ bias0, const float* __restrict__ bias1, const float* __restrict__ bias2,
    const float* __restrict__ res,
    void* __restrict__ out0, void* __restrict__ out1, void* __restrict__ out2,
    int M, int N, int K) {
  __shared__ bf16 As[128 * 32];
  __shared__ bf16 Bs[128 * 32];
  const int tid = threadIdx.x;
  const int w = tid >> 6, l = tid & 63;
  const int wr = w >> 1, wc = w & 1;
  const int col = l & 15, hi = l >> 4;
  const int m0 = blockIdx.y * 128, n0 = blockIdx.x * 128;

  const bf16* BT; const float* bias; void* outp;
  if (EPI == 0) {
    const int z = blockIdx.z;
    BT = (z == 0) ? B0 : (z == 1) ? B1 : B2;
    bias = (z == 0) ? bias0 : (z == 1) ? bias1 : bias2;
    outp = (z == 0) ? out0 : (z == 1) ? out1 : out2;
  } else { BT = B0; bias = bias0; outp = out0; }

  const int srow = l >> 2;          // row within 16-row staging group
  const int scol = (l & 3) * 8;     // element col within BK=32
  f32x4 acc[4][4] = {};

  const int nk = K >> 5;
  for (int kt = 0; kt < nk; ++kt) {
    const int k0 = kt * 32;
#pragma unroll
    for (int j = 0; j < 2; ++j) {
      const int rbase = (w * 2 + j) * 16;
      load_lds16(A + (size_t)(m0 + rbase + srow) * K + k0 + scol, As + (w * 2 + j) * 512);
      load_lds16(BT + (size_t)(n0 + rbase + srow) * K + k0 + scol, Bs + (w * 2 + j) * 512);
    }
    __syncthreads();
    short8v af[4], bfr[4];
#pragma unroll
    for (int i = 0; i < 4; ++i) {
      af[i]  = *(const short8v*)&As[(wr * 64 + i * 16 + col) * 32 + hi * 8];
      bfr[i] = *(const short8v*)&Bs[(wc * 64 + i * 16 + col) * 32 + hi * 8];
    }
#pragma unroll
    for (int mi = 0; mi < 4; ++mi)
#pragma unroll
      for (int ni = 0; ni < 4; ++ni)
        acc[mi][ni] = __builtin_amdgcn_mfma_f32_16x16x32_bf16(af[mi], bfr[ni], acc[mi][ni], 0, 0, 0);
    __syncthreads();
  }

#pragma unroll
  for (int mi = 0; mi < 4; ++mi) {
#pragma unroll
    for (int ni = 0; ni < 4; ++ni) {
#pragma unroll
      for (int r = 0; r < 4; ++r) {
        const int m = m0 + wr * 64 + mi * 16 + hi * 4 + r;
        const int n = n0 + wc * 64 + ni * 16 + col;
        const float vv = acc[mi][ni][r] + bias[n];
        if (EPI == 0) {
          const int bb = m >> 11, ss = m & 2047, hh = n >> 7, dd = n & 127;
          ((bf16*)outp)[(((size_t)bb * 8 + hh) * 2048 + ss) * 128 + dd] = __float2bfloat16(vv);
        } else if (EPI == 1) {
          const size_t idx = (size_t)m * N + n;
          ((float*)outp)[idx] = res[idx] + vv;
        } else {
          const size_t idx = (size_t)m * N + n;
          const float gg = 0.5f * vv * (1.0f + erff(vv * 0.70710678118f));
          ((bf16*)outp)[idx] = __float2bfloat16(gg);
        }
      }
    }
  }
}

// ---------------- causal flash attention: q,k,v [B*NH][S][128] bf16 -> y [B][S][H] bf16 ----------------
__global__ __launch_bounds__(256) void attn_kernel(const bf16* __restrict__ q,
                                                   const bf16* __restrict__ k,
                                                   const bf16* __restrict__ v,
                                                   bf16* __restrict__ y) {
  __shared__ bf16 Ks[32 * 136];      // K tile [32 keys][128 d], padded stride
  __shared__ bf16 Vt[128 * 40];      // V^T tile [128 d][32 keys], padded stride
  __shared__ bf16 Ps[4][16 * 40];    // per-wave P tile [16 q][32 k], padded
  const int qt = blockIdx.x, bh = blockIdx.y;
  const int q0 = qt * 64;
  const int tid = threadIdx.x;
  const int w = tid >> 6, l = tid & 63;
  const int col = l & 15, hi = l >> 4;

  short8v qf[4];
  const bf16* qp = q + ((size_t)bh * 2048 + q0 + w * 16 + col) * 128;
#pragma unroll
  for (int c = 0; c < 4; ++c) qf[c] = *(const short8v*)(qp + c * 32 + hi * 8);

  f32x4 o[8] = {};
  float mx[4] = {-1e30f, -1e30f, -1e30f, -1e30f};
  float sm[4] = {0.f, 0.f, 0.f, 0.f};
  const float scale = 0.08838834764831845f;  // 1/sqrt(128)

  const int nkt = (q0 >> 5) + 2;
  for (int kt = 0; kt < nkt; ++kt) {
    {  // stage K (natural) and V (transposed)
      const int r = tid >> 3, c = (tid & 7) * 16;
      const bf16* ksrc = k + ((size_t)bh * 2048 + kt * 32 + r) * 128 + c;
      *(short8v*)&Ks[r * 136 + c]     = *(const short8v*)ksrc;
      *(short8v*)&Ks[r * 136 + c + 8] = *(const short8v*)(ksrc + 8);
      const bf16* vsrc = v + ((size_t)bh * 2048 + kt * 32 + r) * 128 + c;
      short8v v0 = *(const short8v*)vsrc;
      short8v v1 = *(const short8v*)(vsrc + 8);
#pragma unroll
      for (int i = 0; i < 8; ++i) {
        ((short*)Vt)[(c + i) * 40 + r]     = v0[i];
        ((short*)Vt)[(c + 8 + i) * 40 + r] = v1[i];
      }
    }
    __syncthreads();
    // QK^T: scores [16 q][32 k]
    f32x4 s0 = {0.f, 0.f, 0.f, 0.f}, s1 = {0.f, 0.f, 0.f, 0.f};
#pragma unroll
    for (int c = 0; c < 4; ++c) {
      short8v kf0 = *(const short8v*)&Ks[col * 136 + c * 32 + hi * 8];
      short8v kf1 = *(const short8v*)&Ks[(16 + col) * 136 + c * 32 + hi * 8];
      s0 = __builtin_amdgcn_mfma_f32_16x16x32_bf16(qf[c], kf0, s0, 0, 0, 0);
      s1 = __builtin_amdgcn_mfma_f32_16x16x32_bf16(qf[c], kf1, s1, 0, 0, 0);
    }
    // mask + scale + online softmax (rows replicated over 16-lane groups)
    const int qrow = q0 + w * 16 + hi * 4;
    const int kg0 = kt * 32 + col, kg1 = kt * 32 + 16 + col;
    float al[4];
#pragma unroll
    for (int r = 0; r < 4; ++r) {
      const int qg = qrow + r;
      float a0 = (kg0 <= qg) ? s0[r] * scale : -1e30f;
      float a1 = (kg1 <= qg) ? s1[r] * scale : -1e30f;
      float t = fmaxf(a0, a1);
#pragma unroll
      for (int mm = 1; mm < 16; mm <<= 1) t = fmaxf(t, __shfl_xor(t, mm));
      const float mn = fmaxf(mx[r], t);
      const float aa = __expf(mx[r] - mn);
      const float p0 = __expf(a0 - mn);
      const float p1 = __expf(a1 - mn);
      float ps = p0 + p1;
#pragma unroll
      for (int mm = 1; mm < 16; mm <<= 1) ps += __shfl_xor(ps, mm);
      sm[r] = sm[r] * aa + ps;
      mx[r] = mn; al[r] = aa;
      Ps[w][(hi * 4 + r) * 40 + col]      = __float2bfloat16(p0);
      Ps[w][(hi * 4 + r) * 40 + col + 16] = __float2bfloat16(p1);
    }
#pragma unroll
    for (int db = 0; db < 8; ++db)
#pragma unroll
      for (int r = 0; r < 4; ++r) o[db][r] *= al[r];
    // wave-local LDS round trip for P (C-layout -> A-operand layout)
    asm volatile("s_waitcnt lgkmcnt(0)" ::: "memory");
    short8v pf = *(const short8v*)&Ps[w][col * 40 + hi * 8];
#pragma unroll
    for (int db = 0; db < 8; ++db) {
      short8v vf = *(const short8v*)&Vt[(db * 16 + col) * 40 + hi * 8];
      o[db] = __builtin_amdgcn_mfma_f32_16x16x32_bf16(pf, vf, o[db], 0, 0, 0);
    }
    __syncthreads();
  }
  // epilogue: normalize, write y as [B][S][H]
  const int bb = bh >> 3, hh = bh & 7;
#pragma unroll
  for (int db = 0; db < 8; ++db) {
#pragma unroll
    for (int r = 0; r < 4; ++r) {
      const int qg = q0 + w * 16 + hi * 4 + r;
      y[((size_t)bb * 2048 + qg) * 1024 + hh * 128 + db * 16 + col] =
          __float2bfloat16(o[db][r] / sm[r]);
    }
  }
}

extern "C" void kernel_launch(void* const* d_in, const int* in_sizes, int n_in,
                              void* d_out, int out_size, void* d_ws, size_t ws_size,
                              hipStream_t stream) {
  const float* x    = (const float*)d_in[0];
  const float* ln1g = (const float*)d_in[1];
  const float* ln1b = (const float*)d_in[2];
  const float* ln2g = (const float*)d_in[3];
  const float* ln2b = (const float*)d_in[4];
  const float* Wq   = (const float*)d_in[5];
  const float* bq   = (const float*)d_in[6];
  const float* Wk   = (const float*)d_in[7];
  const float* bk   = (const float*)d_in[8];
  const float* Wv   = (const float*)d_in[9];
  const float* bv   = (const float*)d_in[10];
  const float* Wo   = (const float*)d_in[11];
  const float* bo   = (const float*)d_in[12];
  const float* W1   = (const float*)d_in[13];
  const float* b1   = (const float*)d_in[14];
  const float* W2   = (const float*)d_in[15];
  const float* b2   = (const float*)d_in[16];
  float* out = (float*)d_out;
  char* ws = (char*)d_ws;
  const size_t MB = 1024 * 1024;

  // workspace layout (lifetime-overlapped), 80 MB total
  bf16* WqT = (bf16*)(ws + 0 * MB);
  bf16* WkT = (bf16*)(ws + 2 * MB);
  bf16* WvT = (bf16*)(ws + 4 * MB);
  bf16* WoT = (bf16*)(ws + 6 * MB);
  bf16* W1T = (bf16*)(ws + 8 * MB);    // [4096][1024]
  bf16* W2T = (bf16*)(ws + 16 * MB);   // [1024][4096]
  bf16* h   = (bf16*)(ws + 24 * MB);   // ln1 out, later reused as ln2 out (h2)
  bf16* qb  = (bf16*)(ws + 32 * MB);
  bf16* kb  = (bf16*)(ws + 40 * MB);
  bf16* vb  = (bf16*)(ws + 48 * MB);
  bf16* y   = (bf16*)(ws + 56 * MB);
  bf16* g   = (bf16*)(ws + 32 * MB);   // reuses q/k/v/y region (dead by then)
  float* x1 = (float*)(ws + 64 * MB);  // fp32 residual
  bf16* h2  = h;

  // weight transpose+convert
  tconv<<<dim3(16, 16), 256, 0, stream>>>(Wq, WqT, 1024, 1024);
  tconv<<<dim3(16, 16), 256, 0, stream>>>(Wk, WkT, 1024, 1024);
  tconv<<<dim3(16, 16), 256, 0, stream>>>(Wv, WvT, 1024, 1024);
  tconv<<<dim3(16, 16), 256, 0, stream>>>(Wo, WoT, 1024, 1024);
  tconv<<<dim3(64, 16), 256, 0, stream>>>(W1, W1T, 1024, 4096);
  tconv<<<dim3(16, 64), 256, 0, stream>>>(W2, W2T, 4096, 1024);

  ln_kernel<<<4096, 256, 0, stream>>>(x, ln1g, ln1b, h);

  gemm128<0><<<dim3(8, 32, 3), 256, 0, stream>>>(h, WqT, WkT, WvT, bq, bk, bv, nullptr,
                                                 qb, kb, vb, 4096, 1024, 1024);

  attn_kernel<<<dim3(32, 16), 256, 0, stream>>>(qb, kb, vb, y);

  gemm128<1><<<dim3(8, 32), 256, 0, stream>>>(y, WoT, nullptr, nullptr, bo, nullptr, nullptr,
                                              x, x1, nullptr, nullptr, 4096, 1024, 1024);

  ln_kernel<<<4096, 256, 0, stream>>>(x1, ln2g, ln2b, h2);

  gemm128<2><<<dim3(32, 32), 256, 0, stream>>>(h2, W1T, nullptr, nullptr, b1, nullptr, nullptr,
                                               nullptr, g, nullptr, nullptr, 4096, 4096, 1024);

  gemm128<1><<<dim3(8, 32), 256, 0, stream>>>(g, W2T, nullptr, nullptr, b2, nullptr, nullptr,
                                              x1, out, nullptr, nullptr, 4096, 1024, 4096);
}

// Round 2
// 371.766 us; speedup vs baseline: 1.2036x; 1.2036x over previous
//
#include <hip/hip_runtime.h>
#include <hip/hip_bf16.h>
#include <math.h>

using bf16 = __hip_bfloat16;
typedef __attribute__((ext_vector_type(8))) short short8v;
typedef __attribute__((ext_vector_type(4))) float f32x4;

#define DEV __device__ __forceinline__

// async global->LDS, 16B per lane. LDS dest must be wave-uniform base (HW adds lane*16).
DEV void load_lds16(const bf16* gsrc, bf16* ldst) {
  __builtin_amdgcn_global_load_lds((const __attribute__((address_space(1))) void*)gsrc,
                                   (__attribute__((address_space(3))) void*)ldst, 16, 0, 0);
}

// ---------------- transpose + fp32->bf16 convert: W[K][N] -> WT[N][K] ----------------
__global__ __launch_bounds__(256) void tconv(const float* __restrict__ W, bf16* __restrict__ WT,
                                             int K, int N) {
  __shared__ float tile[64][65];
  const int n0 = blockIdx.x * 64, k0 = blockIdx.y * 64;
  const int tx = threadIdx.x & 15, ty = threadIdx.x >> 4;
#pragma unroll
  for (int p = 0; p < 4; ++p) {
    int r = p * 16 + ty;
    float4 vv = *(const float4*)&W[(size_t)(k0 + r) * N + n0 + tx * 4];
    tile[r][tx * 4 + 0] = vv.x; tile[r][tx * 4 + 1] = vv.y;
    tile[r][tx * 4 + 2] = vv.z; tile[r][tx * 4 + 3] = vv.w;
  }
  __syncthreads();
#pragma unroll
  for (int p = 0; p < 4; ++p) {
    int n = p * 16 + ty;
    bf16* dst = WT + (size_t)(n0 + n) * K + k0 + tx * 4;
#pragma unroll
    for (int j = 0; j < 4; ++j) dst[j] = __float2bfloat16(tile[tx * 4 + j][n]);
  }
}

// ---------------- LayerNorm: fp32 [rows][1024] -> bf16 ----------------
__global__ __launch_bounds__(256) void ln_kernel(const float* __restrict__ x,
                                                 const float* __restrict__ g,
                                                 const float* __restrict__ b,
                                                 bf16* __restrict__ out) {
  const int row = blockIdx.x, t = threadIdx.x;
  const float4 v = ((const float4*)(x + (size_t)row * 1024))[t];
  float s = v.x + v.y + v.z + v.w;
#pragma unroll
  for (int mm = 1; mm < 64; mm <<= 1) s += __shfl_xor(s, mm);
  __shared__ float r1[4], r2[4];
  if ((t & 63) == 0) r1[t >> 6] = s;
  __syncthreads();
  const float mean = (r1[0] + r1[1] + r1[2] + r1[3]) * (1.0f / 1024.0f);
  const float d0 = v.x - mean, d1 = v.y - mean, d2 = v.z - mean, d3 = v.w - mean;
  float s2 = d0 * d0 + d1 * d1 + d2 * d2 + d3 * d3;
#pragma unroll
  for (int mm = 1; mm < 64; mm <<= 1) s2 += __shfl_xor(s2, mm);
  if ((t & 63) == 0) r2[t >> 6] = s2;
  __syncthreads();
  const float var = (r2[0] + r2[1] + r2[2] + r2[3]) * (1.0f / 1024.0f);
  const float rinv = rsqrtf(var + 1e-5f);
  const int c = t * 4;
  bf16* o = out + (size_t)row * 1024 + c;
  o[0] = __float2bfloat16(d0 * rinv * g[c + 0] + b[c + 0]);
  o[1] = __float2bfloat16(d1 * rinv * g[c + 1] + b[c + 1]);
  o[2] = __float2bfloat16(d2 * rinv * g[c + 2] + b[c + 2]);
  o[3] = __float2bfloat16(d3 * rinv * g[c + 3] + b[c + 3]);
}

// ---------------- GEMM: C[M][N] = A[M][K] * BT[N][K]^T + bias, fused epilogues ----------------
template <int EPI>
__global__ __launch_bounds__(256) void gemm128(
    const bf16* __restrict__ A,
    const bf16* __restrict__ B0, const bf16* __restrict__ B1, const bf16* __restrict__ B2,
    const float* __restrict__ bias0, const float* __restrict__ bias1, const float* __restrict__ bias2,
    const float* __restrict__ res,
    void* __restrict__ out0, void* __restrict__ out1, void* __restrict__ out2,
    int M, int N, int K) {
  __shared__ bf16 As[128 * 32];
  __shared__ bf16 Bs[128 * 32];
  const int tid = threadIdx.x;
  const int w = tid >> 6, l = tid & 63;
  const int wr = w >> 1, wc = w & 1;
  const int col = l & 15, hi = l >> 4;
  const int m0 = blockIdx.y * 128, n0 = blockIdx.x * 128;

  const bf16* BT; const float* bias; void* outp;
  if (EPI == 0) {
    const int z = blockIdx.z;
    BT = (z == 0) ? B0 : (z == 1) ? B1 : B2;
    bias = (z == 0) ? bias0 : (z == 1) ? bias1 : bias2;
    outp = (z == 0) ? out0 : (z == 1) ? out1 : out2;
  } else { BT = B0; bias = bias0; outp = out0; }

  const int srow = l >> 2;
  const int scol = (l & 3) * 8;
  f32x4 acc[4][4] = {};

  const int nk = K >> 5;
  for (int kt = 0; kt < nk; ++kt) {
    const int k0 = kt * 32;
#pragma unroll
    for (int j = 0; j < 2; ++j) {
      const int rbase = (w * 2 + j) * 16;
      load_lds16(A + (size_t)(m0 + rbase + srow) * K + k0 + scol, As + (w * 2 + j) * 512);
      load_lds16(BT + (size_t)(n0 + rbase + srow) * K + k0 + scol, Bs + (w * 2 + j) * 512);
    }
    __syncthreads();
    short8v af[4], bfr[4];
#pragma unroll
    for (int i = 0; i < 4; ++i) {
      af[i]  = *(const short8v*)&As[(wr * 64 + i * 16 + col) * 32 + hi * 8];
      bfr[i] = *(const short8v*)&Bs[(wc * 64 + i * 16 + col) * 32 + hi * 8];
    }
#pragma unroll
    for (int mi = 0; mi < 4; ++mi)
#pragma unroll
      for (int ni = 0; ni < 4; ++ni)
        acc[mi][ni] = __builtin_amdgcn_mfma_f32_16x16x32_bf16(af[mi], bfr[ni], acc[mi][ni], 0, 0, 0);
    __syncthreads();
  }

#pragma unroll
  for (int mi = 0; mi < 4; ++mi) {
#pragma unroll
    for (int ni = 0; ni < 4; ++ni) {
#pragma unroll
      for (int r = 0; r < 4; ++r) {
        const int m = m0 + wr * 64 + mi * 16 + hi * 4 + r;
        const int n = n0 + wc * 64 + ni * 16 + col;
        const float vv = acc[mi][ni][r] + bias[n];
        if (EPI == 0) {
          const int bb = m >> 11, ss = m & 2047, hh = n >> 7, dd = n & 127;
          ((bf16*)outp)[(((size_t)bb * 8 + hh) * 2048 + ss) * 128 + dd] = __float2bfloat16(vv);
        } else if (EPI == 1) {
          const size_t idx = (size_t)m * N + n;
          ((float*)outp)[idx] = res[idx] + vv;
        } else {
          const size_t idx = (size_t)m * N + n;
          const float gg = 0.5f * vv * (1.0f + erff(vv * 0.70710678118f));
          ((bf16*)outp)[idx] = __float2bfloat16(gg);
        }
      }
    }
  }
}

// ---------------- causal flash attention v2 ----------------
// q,k,v [B*NH][2048][128] bf16 -> y [B][2048][1024] bf16
// 4 waves x 16 q-rows (QB=64), KVBLK=64, double-buffered K/V staging.
// K in LDS [64][128] XOR-swizzled (idx ^= (row&7)<<3) via pre-swizzled global_load_lds source.
// V^T in LDS [128][72] built with paired ds_write_b32 (conflict-free).
__global__ __launch_bounds__(256) void attn_kernel(const bf16* __restrict__ q,
                                                   const bf16* __restrict__ k,
                                                   const bf16* __restrict__ v,
                                                   bf16* __restrict__ y) {
  __shared__ bf16 Ks[2][64 * 128];
  __shared__ bf16 Vt[2][128 * 72];
  __shared__ bf16 Ps[4][16 * 72];
  const int qt = 31 - blockIdx.x;          // heavy-first dispatch order
  const int bh = blockIdx.y;
  const int q0 = qt * 64;
  const int tid = threadIdx.x;
  const int w = tid >> 6, l = tid & 63;
  const int col = l & 15, hi = l >> 4;

  const bf16* kbase = k + (size_t)bh * 2048 * 128;
  const bf16* vbase = v + (size_t)bh * 2048 * 128;

  // Q fragments (rows q0 + w*16 + col, this wave's 16 rows)
  short8v qf[4];
  const bf16* qp = q + ((size_t)bh * 2048 + q0 + w * 16 + col) * 128;
#pragma unroll
  for (int c = 0; c < 4; ++c) qf[c] = *(const short8v*)(qp + c * 32 + hi * 8);

  // staging lane mapping
  const int klr  = (l >> 4);               // +j*4 = local row within wave's 16 K rows
  const int kblk0 = l & 15;                // 16B block within 256B row
  const int vr   = (l & 31) * 2;           // V: key pair base 0..62
  const int vcb  = (w * 2 + (l >> 5)) * 16;// V: d base (8 groups of 16)

  f32x4 o[8] = {};
  float mx[4] = {-1e30f, -1e30f, -1e30f, -1e30f};
  float sm[4] = {0.f, 0.f, 0.f, 0.f};
  const float scale = 0.08838834764831845f;  // 1/sqrt(128)

  const int nkt = qt + 1;

  // ---- prologue: stage tile 0 into buf 0 ----
  {
#pragma unroll
    for (int j = 0; j < 4; ++j) {
      const int lr = j * 4 + klr;
      const int blk = kblk0 ^ (lr & 7);
      load_lds16(kbase + (size_t)(0 * 64 + w * 16 + lr) * 128 + blk * 8,
                 &Ks[0][w * 2048 + j * 512]);
    }
    const bf16* vsrc = vbase + (size_t)vr * 128 + vcb;
    short8v v00 = *(const short8v*)vsrc;
    short8v v01 = *(const short8v*)(vsrc + 8);
    short8v v10 = *(const short8v*)(vsrc + 128);
    short8v v11 = *(const short8v*)(vsrc + 136);
#pragma unroll
    for (int i = 0; i < 8; ++i) {
      *(unsigned int*)&Vt[0][(vcb + i) * 72 + vr] =
          ((unsigned int)(unsigned short)v00[i]) | (((unsigned int)(unsigned short)v10[i]) << 16);
      *(unsigned int*)&Vt[0][(vcb + 8 + i) * 72 + vr] =
          ((unsigned int)(unsigned short)v01[i]) | (((unsigned int)(unsigned short)v11[i]) << 16);
    }
  }
  __syncthreads();

  for (int kt = 0; kt < nkt; ++kt) {
    const int cur = kt & 1;
    const bool last = (kt + 1 >= nkt);

    // ---- issue next tile's loads early (overlap with compute) ----
    short8v v00, v01, v10, v11;
    if (!last) {
#pragma unroll
      for (int j = 0; j < 4; ++j) {
        const int lr = j * 4 + klr;
        const int blk = kblk0 ^ (lr & 7);
        load_lds16(kbase + (size_t)((kt + 1) * 64 + w * 16 + lr) * 128 + blk * 8,
                   &Ks[cur ^ 1][w * 2048 + j * 512]);
      }
      const bf16* vsrc = vbase + (size_t)((kt + 1) * 64 + vr) * 128 + vcb;
      v00 = *(const short8v*)vsrc;
      v01 = *(const short8v*)(vsrc + 8);
      v10 = *(const short8v*)(vsrc + 128);
      v11 = *(const short8v*)(vsrc + 136);
    }

    // ---- QK^T: scores [16 q][64 k] per wave ----
    f32x4 s[4] = {};
#pragma unroll
    for (int c = 0; c < 4; ++c) {
#pragma unroll
      for (int kg = 0; kg < 4; ++kg) {
        const int kr = kg * 16 + col;
        short8v kf = *(const short8v*)&Ks[cur][kr * 128 + ((c * 32 + hi * 8) ^ ((col & 7) << 3))];
        s[kg] = __builtin_amdgcn_mfma_f32_16x16x32_bf16(qf[c], kf, s[kg], 0, 0, 0);
      }
    }

    // ---- online softmax (rows live in 16-lane col groups) ----
    const bool diag = (kt == qt);
    const int qrl = w * 16 + hi * 4;     // local q row base for this lane
    float al[4];
#pragma unroll
    for (int r = 0; r < 4; ++r) {
      float a0 = s[0][r] * scale, a1 = s[1][r] * scale;
      float a2 = s[2][r] * scale, a3 = s[3][r] * scale;
      if (diag) {
        const int qr = qrl + r;
        if (0 * 16 + col > qr) a0 = -1e30f;
        if (1 * 16 + col > qr) a1 = -1e30f;
        if (2 * 16 + col > qr) a2 = -1e30f;
        if (3 * 16 + col > qr) a3 = -1e30f;
      }
      float t = fmaxf(fmaxf(a0, a1), fmaxf(a2, a3));
#pragma unroll
      for (int mm = 1; mm < 16; mm <<= 1) t = fmaxf(t, __shfl_xor(t, mm));
      const float mn = fmaxf(mx[r], t);
      const float aa = __expf(mx[r] - mn);
      const float p0 = __expf(a0 - mn), p1 = __expf(a1 - mn);
      const float p2 = __expf(a2 - mn), p3 = __expf(a3 - mn);
      float ps = (p0 + p1) + (p2 + p3);
#pragma unroll
      for (int mm = 1; mm < 16; mm <<= 1) ps += __shfl_xor(ps, mm);
      sm[r] = sm[r] * aa + ps;
      mx[r] = mn; al[r] = aa;
      const int prow = (hi * 4 + r) * 72;
      Ps[w][prow + col]      = __float2bfloat16(p0);
      Ps[w][prow + col + 16] = __float2bfloat16(p1);
      Ps[w][prow + col + 32] = __float2bfloat16(p2);
      Ps[w][prow + col + 48] = __float2bfloat16(p3);
    }
#pragma unroll
    for (int db = 0; db < 8; ++db)
#pragma unroll
      for (int r = 0; r < 4; ++r) o[db][r] *= al[r];

    // ---- write next V tile into other buffer (global loads have landed by now) ----
    if (!last) {
#pragma unroll
      for (int i = 0; i < 8; ++i) {
        *(unsigned int*)&Vt[cur ^ 1][(vcb + i) * 72 + vr] =
            ((unsigned int)(unsigned short)v00[i]) | (((unsigned int)(unsigned short)v10[i]) << 16);
        *(unsigned int*)&Vt[cur ^ 1][(vcb + 8 + i) * 72 + vr] =
            ((unsigned int)(unsigned short)v01[i]) | (((unsigned int)(unsigned short)v11[i]) << 16);
      }
    }

    // ---- PV: o += P @ V ----
#pragma unroll
    for (int ks = 0; ks < 2; ++ks) {
      short8v pf = *(const short8v*)&Ps[w][col * 72 + ks * 32 + hi * 8];
#pragma unroll
      for (int db = 0; db < 8; ++db) {
        short8v vf = *(const short8v*)&Vt[cur][(db * 16 + col) * 72 + ks * 32 + hi * 8];
        o[db] = __builtin_amdgcn_mfma_f32_16x16x32_bf16(pf, vf, o[db], 0, 0, 0);
      }
    }
    __syncthreads();
  }

  // ---- epilogue: normalize, write y as [B][S][H] ----
  const int bb = bh >> 3, hh = bh & 7;
  float inv[4];
#pragma unroll
  for (int r = 0; r < 4; ++r) inv[r] = 1.0f / sm[r];
#pragma unroll
  for (int db = 0; db < 8; ++db) {
#pragma unroll
    for (int r = 0; r < 4; ++r) {
      const int qg = q0 + w * 16 + hi * 4 + r;
      y[((size_t)bb * 2048 + qg) * 1024 + hh * 128 + db * 16 + col] =
          __float2bfloat16(o[db][r] * inv[r]);
    }
  }
}

extern "C" void kernel_launch(void* const* d_in, const int* in_sizes, int n_in,
                              void* d_out, int out_size, void* d_ws, size_t ws_size,
                              hipStream_t stream) {
  const float* x    = (const float*)d_in[0];
  const float* ln1g = (const float*)d_in[1];
  const float* ln1b = (const float*)d_in[2];
  const float* ln2g = (const float*)d_in[3];
  const float* ln2b = (const float*)d_in[4];
  const float* Wq   = (const float*)d_in[5];
  const float* bq   = (const float*)d_in[6];
  const float* Wk   = (const float*)d_in[7];
  const float* bk   = (const float*)d_in[8];
  const float* Wv   = (const float*)d_in[9];
  const float* bv   = (const float*)d_in[10];
  const float* Wo   = (const float*)d_in[11];
  const float* bo   = (const float*)d_in[12];
  const float* W1   = (const float*)d_in[13];
  const float* b1   = (const float*)d_in[14];
  const float* W2   = (const float*)d_in[15];
  const float* b2   = (const float*)d_in[16];
  float* out = (float*)d_out;
  char* ws = (char*)d_ws;
  const size_t MB = 1024 * 1024;

  bf16* WqT = (bf16*)(ws + 0 * MB);
  bf16* WkT = (bf16*)(ws + 2 * MB);
  bf16* WvT = (bf16*)(ws + 4 * MB);
  bf16* WoT = (bf16*)(ws + 6 * MB);
  bf16* W1T = (bf16*)(ws + 8 * MB);
  bf16* W2T = (bf16*)(ws + 16 * MB);
  bf16* h   = (bf16*)(ws + 24 * MB);
  bf16* qb  = (bf16*)(ws + 32 * MB);
  bf16* kb  = (bf16*)(ws + 40 * MB);
  bf16* vb  = (bf16*)(ws + 48 * MB);
  bf16* y   = (bf16*)(ws + 56 * MB);
  bf16* g   = (bf16*)(ws + 32 * MB);
  float* x1 = (float*)(ws + 64 * MB);
  bf16* h2  = h;

  tconv<<<dim3(16, 16), 256, 0, stream>>>(Wq, WqT, 1024, 1024);
  tconv<<<dim3(16, 16), 256, 0, stream>>>(Wk, WkT, 1024, 1024);
  tconv<<<dim3(16, 16), 256, 0, stream>>>(Wv, WvT, 1024, 1024);
  tconv<<<dim3(16, 16), 256, 0, stream>>>(Wo, WoT, 1024, 1024);
  tconv<<<dim3(64, 16), 256, 0, stream>>>(W1, W1T, 1024, 4096);
  tconv<<<dim3(16, 64), 256, 0, stream>>>(W2, W2T, 4096, 1024);

  ln_kernel<<<4096, 256, 0, stream>>>(x, ln1g, ln1b, h);

  gemm128<0><<<dim3(8, 32, 3), 256, 0, stream>>>(h, WqT, WkT, WvT, bq, bk, bv, nullptr,
                                                 qb, kb, vb, 4096, 1024, 1024);

  attn_kernel<<<dim3(32, 16), 256, 0, stream>>>(qb, kb, vb, y);

  gemm128<1><<<dim3(8, 32), 256, 0, stream>>>(y, WoT, nullptr, nullptr, bo, nullptr, nullptr,
                                              x, x1, nullptr, nullptr, 4096, 1024, 1024);

  ln_kernel<<<4096, 256, 0, stream>>>(x1, ln2g, ln2b, h2);

  gemm128<2><<<dim3(32, 32), 256, 0, stream>>>(h2, W1T, nullptr, nullptr, b1, nullptr, nullptr,
                                               nullptr, g, nullptr, nullptr, 4096, 4096, 1024);

  gemm128<1><<<dim3(8, 32), 256, 0, stream>>>(g, W2T, nullptr, nullptr, b2, nullptr, nullptr,
                                              x1, out, nullptr, nullptr, 4096, 1024, 4096);
}

// Round 3
// 323.600 us; speedup vs baseline: 1.3827x; 1.1488x over previous
//
#include <hip/hip_runtime.h>
#include <hip/hip_bf16.h>
#include <math.h>

using bf16 = __hip_bfloat16;
typedef __attribute__((ext_vector_type(8))) short short8v;
typedef __attribute__((ext_vector_type(4))) float f32x4;

#define DEV __device__ __forceinline__

// async global->LDS, 16B per lane. LDS dest must be wave-uniform base (HW adds lane*16).
DEV void load_lds16(const bf16* gsrc, bf16* ldst) {
  __builtin_amdgcn_global_load_lds((const __attribute__((address_space(1))) void*)gsrc,
                                   (__attribute__((address_space(3))) void*)ldst, 16, 0, 0);
}

// ---------------- all weight transposes+converts in ONE launch ----------------
// routing: blocks 0..1023 -> Wq/Wk/Wv/Wo (16x16 tiles each); 1024..2047 -> W1; 2048..3071 -> W2
__global__ __launch_bounds__(256) void tconv_all(
    const float* __restrict__ Wq, const float* __restrict__ Wk, const float* __restrict__ Wv,
    const float* __restrict__ Wo, const float* __restrict__ W1, const float* __restrict__ W2,
    bf16* __restrict__ WqT, bf16* __restrict__ WkT, bf16* __restrict__ WvT,
    bf16* __restrict__ WoT, bf16* __restrict__ W1T, bf16* __restrict__ W2T) {
  __shared__ float tile[64][65];
  const int b = blockIdx.x;
  const float* W; bf16* WT; int K, N, n0, k0;
  if (b < 1024) {
    const int which = b >> 8, t = b & 255;
    W  = (which == 0) ? Wq  : (which == 1) ? Wk  : (which == 2) ? Wv  : Wo;
    WT = (which == 0) ? WqT : (which == 1) ? WkT : (which == 2) ? WvT : WoT;
    K = 1024; N = 1024; n0 = (t & 15) * 64; k0 = (t >> 4) * 64;
  } else if (b < 2048) {
    const int t = b - 1024;
    W = W1; WT = W1T; K = 1024; N = 4096; n0 = (t & 63) * 64; k0 = (t >> 6) * 64;
  } else {
    const int t = b - 2048;
    W = W2; WT = W2T; K = 4096; N = 1024; n0 = (t & 15) * 64; k0 = (t >> 4) * 64;
  }
  const int tx = threadIdx.x & 15, ty = threadIdx.x >> 4;
#pragma unroll
  for (int p = 0; p < 4; ++p) {
    int r = p * 16 + ty;
    float4 vv = *(const float4*)&W[(size_t)(k0 + r) * N + n0 + tx * 4];
    tile[r][tx * 4 + 0] = vv.x; tile[r][tx * 4 + 1] = vv.y;
    tile[r][tx * 4 + 2] = vv.z; tile[r][tx * 4 + 3] = vv.w;
  }
  __syncthreads();
#pragma unroll
  for (int p = 0; p < 4; ++p) {
    int n = p * 16 + ty;
    bf16* dst = WT + (size_t)(n0 + n) * K + k0 + tx * 4;
#pragma unroll
    for (int j = 0; j < 4; ++j) dst[j] = __float2bfloat16(tile[tx * 4 + j][n]);
  }
}

// ---------------- LayerNorm: fp32 [rows][1024] -> bf16 ----------------
__global__ __launch_bounds__(256) void ln_kernel(const float* __restrict__ x,
                                                 const float* __restrict__ g,
                                                 const float* __restrict__ b,
                                                 bf16* __restrict__ out) {
  const int row = blockIdx.x, t = threadIdx.x;
  const float4 v = ((const float4*)(x + (size_t)row * 1024))[t];
  float s = v.x + v.y + v.z + v.w;
#pragma unroll
  for (int mm = 1; mm < 64; mm <<= 1) s += __shfl_xor(s, mm);
  __shared__ float r1[4], r2[4];
  if ((t & 63) == 0) r1[t >> 6] = s;
  __syncthreads();
  const float mean = (r1[0] + r1[1] + r1[2] + r1[3]) * (1.0f / 1024.0f);
  const float d0 = v.x - mean, d1 = v.y - mean, d2 = v.z - mean, d3 = v.w - mean;
  float s2 = d0 * d0 + d1 * d1 + d2 * d2 + d3 * d3;
#pragma unroll
  for (int mm = 1; mm < 64; mm <<= 1) s2 += __shfl_xor(s2, mm);
  if ((t & 63) == 0) r2[t >> 6] = s2;
  __syncthreads();
  const float var = (r2[0] + r2[1] + r2[2] + r2[3]) * (1.0f / 1024.0f);
  const float rinv = rsqrtf(var + 1e-5f);
  const int c = t * 4;
  bf16* o = out + (size_t)row * 1024 + c;
  o[0] = __float2bfloat16(d0 * rinv * g[c + 0] + b[c + 0]);
  o[1] = __float2bfloat16(d1 * rinv * g[c + 1] + b[c + 1]);
  o[2] = __float2bfloat16(d2 * rinv * g[c + 2] + b[c + 2]);
  o[3] = __float2bfloat16(d3 * rinv * g[c + 3] + b[c + 3]);
}

// ---------------- GEMM: C[M][N] = A[M][K] * BT[N][K]^T + bias ----------------
// template MI: wave-tile M-fragments; BM = 32*MI (MI=4 -> 128x128 tile, MI=2 -> 64x128).
// EPI 0: merged-QKV bf16 out with [3][B][NH][S][HD] remap (zz = n0>>10)
// EPI 1: fp32 out = res + acc + bias
// EPI 2: bf16 out = gelu(acc + bias)
template <int EPI, int MI>
__global__ __launch_bounds__(256) void gemm128(
    const bf16* __restrict__ A, const bf16* __restrict__ BT,
    const float* __restrict__ bias0, const float* __restrict__ bias1, const float* __restrict__ bias2,
    const float* __restrict__ res, void* __restrict__ outp,
    int M, int N, int K) {
  __shared__ bf16 As[MI * 1024];
  __shared__ bf16 Bs[128 * 32];
  const int tid = threadIdx.x;
  const int w = tid >> 6, l = tid & 63;
  const int wr = w >> 1, wc = w & 1;
  const int col = l & 15, hi = l >> 4;
  const int m0 = blockIdx.y * (32 * MI), n0 = blockIdx.x * 128;

  const float* bias;
  int zz = 0;
  if (EPI == 0) {
    zz = n0 >> 10;
    bias = ((zz == 0) ? bias0 : (zz == 1) ? bias1 : bias2) - (zz << 10);
  } else {
    bias = bias0;
  }

  const int srow = l >> 2;
  const int scol = (l & 3) * 8;
  f32x4 acc[MI][4] = {};

  const int nk = K >> 5;
  for (int kt = 0; kt < nk; ++kt) {
    const int k0 = kt * 32;
#pragma unroll
    for (int j = 0; j < MI / 2; ++j) {
      const int grp = w * (MI / 2) + j;
      load_lds16(A + (size_t)(m0 + grp * 16 + srow) * K + k0 + scol, As + grp * 512);
    }
#pragma unroll
    for (int j = 0; j < 2; ++j) {
      const int grp = w * 2 + j;
      load_lds16(BT + (size_t)(n0 + grp * 16 + srow) * K + k0 + scol, Bs + grp * 512);
    }
    __syncthreads();
    short8v af[MI], bfr[4];
#pragma unroll
    for (int i = 0; i < MI; ++i)
      af[i] = *(const short8v*)&As[(wr * (16 * MI) + i * 16 + col) * 32 + hi * 8];
#pragma unroll
    for (int i = 0; i < 4; ++i)
      bfr[i] = *(const short8v*)&Bs[(wc * 64 + i * 16 + col) * 32 + hi * 8];
#pragma unroll
    for (int mi = 0; mi < MI; ++mi)
#pragma unroll
      for (int ni = 0; ni < 4; ++ni)
        acc[mi][ni] = __builtin_amdgcn_mfma_f32_16x16x32_bf16(af[mi], bfr[ni], acc[mi][ni], 0, 0, 0);
    __syncthreads();
  }

#pragma unroll
  for (int mi = 0; mi < MI; ++mi) {
#pragma unroll
    for (int ni = 0; ni < 4; ++ni) {
#pragma unroll
      for (int r = 0; r < 4; ++r) {
        const int m = m0 + wr * (16 * MI) + mi * 16 + hi * 4 + r;
        const int n = n0 + wc * 64 + ni * 16 + col;
        const float vv = acc[mi][ni][r] + bias[n];
        if (EPI == 0) {
          const int bb = m >> 11, ss = m & 2047;
          const int n1 = n - (zz << 10);
          const int hh = n1 >> 7, dd = n1 & 127;
          ((bf16*)outp)[(size_t)zz * 4194304 + (((size_t)bb * 8 + hh) * 2048 + ss) * 128 + dd] =
              __float2bfloat16(vv);
        } else if (EPI == 1) {
          const size_t idx = (size_t)m * N + n;
          ((float*)outp)[idx] = res[idx] + vv;
        } else {
          const size_t idx = (size_t)m * N + n;
          const float gg = 0.5f * vv * (1.0f + erff(vv * 0.70710678118f));
          ((bf16*)outp)[idx] = __float2bfloat16(gg);
        }
      }
    }
  }
}

// ---------------- causal flash attention v3: balanced pairing ----------------
// Block p handles q-tiles {31-p, p} (64 rows each) sequentially -> every block
// does exactly 33 key-tile iterations. Grid (16,16) = 256 blocks, 1/CU.
__global__ __launch_bounds__(256) void attn_kernel(const bf16* __restrict__ q,
                                                   const bf16* __restrict__ k,
                                                   const bf16* __restrict__ v,
                                                   bf16* __restrict__ y) {
  __shared__ bf16 Ks[2][64 * 128];
  __shared__ bf16 Vt[2][128 * 72];
  __shared__ bf16 Ps[4][16 * 72];
  const int p = blockIdx.x;
  const int bh = blockIdx.y;
  const int tid = threadIdx.x;
  const int w = tid >> 6, l = tid & 63;
  const int col = l & 15, hi = l >> 4;

  const bf16* kbase = k + (size_t)bh * 2048 * 128;
  const bf16* vbase = v + (size_t)bh * 2048 * 128;
  const int bb = bh >> 3, hh = bh & 7;

  // staging lane mapping
  const int klr = (l >> 4);                 // +j*4 = local row within wave's 16 K rows
  const int kblk0 = l & 15;                 // 16B block within 256B row
  const int vr = (l & 31) * 2;              // V: key pair base 0..62
  const int vcb = (w * 2 + (l >> 5)) * 16;  // V: d base (8 groups of 16)

  const float scale = 0.08838834764831845f;  // 1/sqrt(128)

  for (int half = 0; half < 2; ++half) {
    const int qt = half ? p : (31 - p);
    const int q0 = qt * 64;
    const int nkt = qt + 1;

    short8v qf[4];
    const bf16* qp = q + ((size_t)bh * 2048 + q0 + w * 16 + col) * 128;
#pragma unroll
    for (int c = 0; c < 4; ++c) qf[c] = *(const short8v*)(qp + c * 32 + hi * 8);

    f32x4 o[8] = {};
    float mx[4] = {-1e30f, -1e30f, -1e30f, -1e30f};
    float sm[4] = {0.f, 0.f, 0.f, 0.f};

    // ---- prologue: stage tile 0 into buf 0 ----
    {
#pragma unroll
      for (int j = 0; j < 4; ++j) {
        const int lr = j * 4 + klr;
        const int blk = kblk0 ^ (lr & 7);
        load_lds16(kbase + (size_t)(w * 16 + lr) * 128 + blk * 8, &Ks[0][w * 2048 + j * 512]);
      }
      const bf16* vsrc = vbase + (size_t)vr * 128 + vcb;
      short8v v00 = *(const short8v*)vsrc;
      short8v v01 = *(const short8v*)(vsrc + 8);
      short8v v10 = *(const short8v*)(vsrc + 128);
      short8v v11 = *(const short8v*)(vsrc + 136);
#pragma unroll
      for (int i = 0; i < 8; ++i) {
        *(unsigned int*)&Vt[0][(vcb + i) * 72 + vr] =
            ((unsigned int)(unsigned short)v00[i]) | (((unsigned int)(unsigned short)v10[i]) << 16);
        *(unsigned int*)&Vt[0][(vcb + 8 + i) * 72 + vr] =
            ((unsigned int)(unsigned short)v01[i]) | (((unsigned int)(unsigned short)v11[i]) << 16);
      }
    }
    __syncthreads();

    for (int kt = 0; kt < nkt; ++kt) {
      const int cur = kt & 1;
      const bool last = (kt + 1 >= nkt);

      // ---- issue next tile's loads early (overlap with compute) ----
      short8v v00, v01, v10, v11;
      if (!last) {
#pragma unroll
        for (int j = 0; j < 4; ++j) {
          const int lr = j * 4 + klr;
          const int blk = kblk0 ^ (lr & 7);
          load_lds16(kbase + (size_t)((kt + 1) * 64 + w * 16 + lr) * 128 + blk * 8,
                     &Ks[cur ^ 1][w * 2048 + j * 512]);
        }
        const bf16* vsrc = vbase + (size_t)((kt + 1) * 64 + vr) * 128 + vcb;
        v00 = *(const short8v*)vsrc;
        v01 = *(const short8v*)(vsrc + 8);
        v10 = *(const short8v*)(vsrc + 128);
        v11 = *(const short8v*)(vsrc + 136);
      }

      // ---- QK^T: scores [16 q][64 k] per wave ----
      f32x4 s[4] = {};
#pragma unroll
      for (int c = 0; c < 4; ++c) {
#pragma unroll
        for (int kg = 0; kg < 4; ++kg) {
          const int kr = kg * 16 + col;
          short8v kf = *(const short8v*)&Ks[cur][kr * 128 + ((c * 32 + hi * 8) ^ ((col & 7) << 3))];
          s[kg] = __builtin_amdgcn_mfma_f32_16x16x32_bf16(qf[c], kf, s[kg], 0, 0, 0);
        }
      }

      // ---- online softmax ----
      const bool diag = (kt == qt);
      const int qrl = w * 16 + hi * 4;
      float al[4];
#pragma unroll
      for (int r = 0; r < 4; ++r) {
        float a0 = s[0][r] * scale, a1 = s[1][r] * scale;
        float a2 = s[2][r] * scale, a3 = s[3][r] * scale;
        if (diag) {
          const int qr = qrl + r;
          if (0 * 16 + col > qr) a0 = -1e30f;
          if (1 * 16 + col > qr) a1 = -1e30f;
          if (2 * 16 + col > qr) a2 = -1e30f;
          if (3 * 16 + col > qr) a3 = -1e30f;
        }
        float t = fmaxf(fmaxf(a0, a1), fmaxf(a2, a3));
#pragma unroll
        for (int mm = 1; mm < 16; mm <<= 1) t = fmaxf(t, __shfl_xor(t, mm));
        const float mn = fmaxf(mx[r], t);
        const float aa = __expf(mx[r] - mn);
        const float p0 = __expf(a0 - mn), p1 = __expf(a1 - mn);
        const float p2 = __expf(a2 - mn), p3 = __expf(a3 - mn);
        float ps = (p0 + p1) + (p2 + p3);
#pragma unroll
        for (int mm = 1; mm < 16; mm <<= 1) ps += __shfl_xor(ps, mm);
        sm[r] = sm[r] * aa + ps;
        mx[r] = mn; al[r] = aa;
        const int prow = (hi * 4 + r) * 72;
        Ps[w][prow + col]      = __float2bfloat16(p0);
        Ps[w][prow + col + 16] = __float2bfloat16(p1);
        Ps[w][prow + col + 32] = __float2bfloat16(p2);
        Ps[w][prow + col + 48] = __float2bfloat16(p3);
      }
#pragma unroll
      for (int db = 0; db < 8; ++db)
#pragma unroll
        for (int r = 0; r < 4; ++r) o[db][r] *= al[r];

      // ---- write next V tile into other buffer ----
      if (!last) {
#pragma unroll
        for (int i = 0; i < 8; ++i) {
          *(unsigned int*)&Vt[cur ^ 1][(vcb + i) * 72 + vr] =
              ((unsigned int)(unsigned short)v00[i]) | (((unsigned int)(unsigned short)v10[i]) << 16);
          *(unsigned int*)&Vt[cur ^ 1][(vcb + 8 + i) * 72 + vr] =
              ((unsigned int)(unsigned short)v01[i]) | (((unsigned int)(unsigned short)v11[i]) << 16);
        }
      }

      // ---- PV: o += P @ V ----
#pragma unroll
      for (int ks = 0; ks < 2; ++ks) {
        short8v pf = *(const short8v*)&Ps[w][col * 72 + ks * 32 + hi * 8];
#pragma unroll
        for (int db = 0; db < 8; ++db) {
          short8v vf = *(const short8v*)&Vt[cur][(db * 16 + col) * 72 + ks * 32 + hi * 8];
          o[db] = __builtin_amdgcn_mfma_f32_16x16x32_bf16(pf, vf, o[db], 0, 0, 0);
        }
      }
      __syncthreads();
    }

    // ---- epilogue: normalize, write y as [B][S][H] ----
    float inv[4];
#pragma unroll
    for (int r = 0; r < 4; ++r) inv[r] = 1.0f / sm[r];
#pragma unroll
    for (int db = 0; db < 8; ++db) {
#pragma unroll
      for (int r = 0; r < 4; ++r) {
        const int qg = q0 + w * 16 + hi * 4 + r;
        y[((size_t)bb * 2048 + qg) * 1024 + hh * 128 + db * 16 + col] =
            __float2bfloat16(o[db][r] * inv[r]);
      }
    }
  }
}

extern "C" void kernel_launch(void* const* d_in, const int* in_sizes, int n_in,
                              void* d_out, int out_size, void* d_ws, size_t ws_size,
                              hipStream_t stream) {
  const float* x    = (const float*)d_in[0];
  const float* ln1g = (const float*)d_in[1];
  const float* ln1b = (const float*)d_in[2];
  const float* ln2g = (const float*)d_in[3];
  const float* ln2b = (const float*)d_in[4];
  const float* Wq   = (const float*)d_in[5];
  const float* bq   = (const float*)d_in[6];
  const float* Wk   = (const float*)d_in[7];
  const float* bk   = (const float*)d_in[8];
  const float* Wv   = (const float*)d_in[9];
  const float* bv   = (const float*)d_in[10];
  const float* Wo   = (const float*)d_in[11];
  const float* bo   = (const float*)d_in[12];
  const float* W1   = (const float*)d_in[13];
  const float* b1   = (const float*)d_in[14];
  const float* W2   = (const float*)d_in[15];
  const float* b2   = (const float*)d_in[16];
  float* out = (float*)d_out;
  char* ws = (char*)d_ws;
  const size_t MB = 1024 * 1024;

  bf16* WqT = (bf16*)(ws + 0 * MB);   // [3072][1024] merged qkv starts here
  bf16* WkT = (bf16*)(ws + 2 * MB);
  bf16* WvT = (bf16*)(ws + 4 * MB);
  bf16* WoT = (bf16*)(ws + 6 * MB);
  bf16* W1T = (bf16*)(ws + 8 * MB);   // [4096][1024]
  bf16* W2T = (bf16*)(ws + 16 * MB);  // [1024][4096]
  bf16* h   = (bf16*)(ws + 24 * MB);
  bf16* qb  = (bf16*)(ws + 32 * MB);  // qkv base: q,k,v contiguous 8MB each
  bf16* kb  = (bf16*)(ws + 40 * MB);
  bf16* vb  = (bf16*)(ws + 48 * MB);
  bf16* y   = (bf16*)(ws + 56 * MB);
  bf16* g   = (bf16*)(ws + 32 * MB);
  float* x1 = (float*)(ws + 64 * MB);
  bf16* h2  = h;

  tconv_all<<<3072, 256, 0, stream>>>(Wq, Wk, Wv, Wo, W1, W2, WqT, WkT, WvT, WoT, W1T, W2T);

  ln_kernel<<<4096, 256, 0, stream>>>(x, ln1g, ln1b, h);

  // merged QKV: N=3072, out remap into qb/kb/vb
  gemm128<0, 4><<<dim3(24, 32), 256, 0, stream>>>(h, WqT, bq, bk, bv, nullptr, qb,
                                                  4096, 3072, 1024);

  attn_kernel<<<dim3(16, 16), 256, 0, stream>>>(qb, kb, vb, y);

  gemm128<1, 2><<<dim3(8, 64), 256, 0, stream>>>(y, WoT, bo, nullptr, nullptr, x, x1,
                                                 4096, 1024, 1024);

  ln_kernel<<<4096, 256, 0, stream>>>(x1, ln2g, ln2b, h2);

  gemm128<2, 4><<<dim3(32, 32), 256, 0, stream>>>(h2, W1T, b1, nullptr, nullptr, nullptr, g,
                                                  4096, 4096, 1024);

  gemm128<1, 2><<<dim3(8, 64), 256, 0, stream>>>(g, W2T, b2, nullptr, nullptr, x1, out,
                                                 4096, 1024, 4096);
}

// Round 4
// 296.832 us; speedup vs baseline: 1.5074x; 1.0902x over previous
//
#include <hip/hip_runtime.h>
#include <hip/hip_bf16.h>
#include <math.h>

using bf16 = __hip_bfloat16;
typedef __attribute__((ext_vector_type(8))) short short8v;
typedef __attribute__((ext_vector_type(4))) float f32x4;

#define DEV __device__ __forceinline__

// async global->LDS, 16B per lane. LDS dest must be wave-uniform base (HW adds lane*16).
DEV void load_lds16(const bf16* gsrc, bf16* ldst) {
  __builtin_amdgcn_global_load_lds((const __attribute__((address_space(1))) void*)gsrc,
                                   (__attribute__((address_space(3))) void*)ldst, 16, 0, 0);
}

// ---------------- all weight transposes+converts in ONE launch ----------------
__global__ __launch_bounds__(256) void tconv_all(
    const float* __restrict__ Wq, const float* __restrict__ Wk, const float* __restrict__ Wv,
    const float* __restrict__ Wo, const float* __restrict__ W1, const float* __restrict__ W2,
    bf16* __restrict__ WqT, bf16* __restrict__ WkT, bf16* __restrict__ WvT,
    bf16* __restrict__ WoT, bf16* __restrict__ W1T, bf16* __restrict__ W2T) {
  __shared__ float tile[64][65];
  const int b = blockIdx.x;
  const float* W; bf16* WT; int K, N, n0, k0;
  if (b < 1024) {
    const int which = b >> 8, t = b & 255;
    W  = (which == 0) ? Wq  : (which == 1) ? Wk  : (which == 2) ? Wv  : Wo;
    WT = (which == 0) ? WqT : (which == 1) ? WkT : (which == 2) ? WvT : WoT;
    K = 1024; N = 1024; n0 = (t & 15) * 64; k0 = (t >> 4) * 64;
  } else if (b < 2048) {
    const int t = b - 1024;
    W = W1; WT = W1T; K = 1024; N = 4096; n0 = (t & 63) * 64; k0 = (t >> 6) * 64;
  } else {
    const int t = b - 2048;
    W = W2; WT = W2T; K = 4096; N = 1024; n0 = (t & 15) * 64; k0 = (t >> 4) * 64;
  }
  const int tx = threadIdx.x & 15, ty = threadIdx.x >> 4;
#pragma unroll
  for (int p = 0; p < 4; ++p) {
    int r = p * 16 + ty;
    float4 vv = *(const float4*)&W[(size_t)(k0 + r) * N + n0 + tx * 4];
    tile[r][tx * 4 + 0] = vv.x; tile[r][tx * 4 + 1] = vv.y;
    tile[r][tx * 4 + 2] = vv.z; tile[r][tx * 4 + 3] = vv.w;
  }
  __syncthreads();
#pragma unroll
  for (int p = 0; p < 4; ++p) {
    int n = p * 16 + ty;
    bf16* dst = WT + (size_t)(n0 + n) * K + k0 + tx * 4;
#pragma unroll
    for (int j = 0; j < 4; ++j) dst[j] = __float2bfloat16(tile[tx * 4 + j][n]);
  }
}

// ---------------- LayerNorm: fp32 [rows][1024] -> bf16 ----------------
__global__ __launch_bounds__(256) void ln_kernel(const float* __restrict__ x,
                                                 const float* __restrict__ g,
                                                 const float* __restrict__ b,
                                                 bf16* __restrict__ out) {
  const int row = blockIdx.x, t = threadIdx.x;
  const float4 v = ((const float4*)(x + (size_t)row * 1024))[t];
  float s = v.x + v.y + v.z + v.w;
#pragma unroll
  for (int mm = 1; mm < 64; mm <<= 1) s += __shfl_xor(s, mm);
  __shared__ float r1[4], r2[4];
  if ((t & 63) == 0) r1[t >> 6] = s;
  __syncthreads();
  const float mean = (r1[0] + r1[1] + r1[2] + r1[3]) * (1.0f / 1024.0f);
  const float d0 = v.x - mean, d1 = v.y - mean, d2 = v.z - mean, d3 = v.w - mean;
  float s2 = d0 * d0 + d1 * d1 + d2 * d2 + d3 * d3;
#pragma unroll
  for (int mm = 1; mm < 64; mm <<= 1) s2 += __shfl_xor(s2, mm);
  if ((t & 63) == 0) r2[t >> 6] = s2;
  __syncthreads();
  const float var = (r2[0] + r2[1] + r2[2] + r2[3]) * (1.0f / 1024.0f);
  const float rinv = rsqrtf(var + 1e-5f);
  const int c = t * 4;
  bf16* o = out + (size_t)row * 1024 + c;
  o[0] = __float2bfloat16(d0 * rinv * g[c + 0] + b[c + 0]);
  o[1] = __float2bfloat16(d1 * rinv * g[c + 1] + b[c + 1]);
  o[2] = __float2bfloat16(d2 * rinv * g[c + 2] + b[c + 2]);
  o[3] = __float2bfloat16(d3 * rinv * g[c + 3] + b[c + 3]);
}

// ---------------- GEMM: C[M][N] = A[M][K] * BT[N][K]^T + bias ----------------
template <int EPI, int MI>
__global__ __launch_bounds__(256) void gemm128(
    const bf16* __restrict__ A, const bf16* __restrict__ BT,
    const float* __restrict__ bias0, const float* __restrict__ bias1, const float* __restrict__ bias2,
    const float* __restrict__ res, void* __restrict__ outp,
    int M, int N, int K) {
  __shared__ bf16 As[MI * 1024];
  __shared__ bf16 Bs[128 * 32];
  const int tid = threadIdx.x;
  const int w = tid >> 6, l = tid & 63;
  const int wr = w >> 1, wc = w & 1;
  const int col = l & 15, hi = l >> 4;
  const int m0 = blockIdx.y * (32 * MI), n0 = blockIdx.x * 128;

  const float* bias;
  int zz = 0;
  if (EPI == 0) {
    zz = n0 >> 10;
    bias = ((zz == 0) ? bias0 : (zz == 1) ? bias1 : bias2) - (zz << 10);
  } else {
    bias = bias0;
  }

  const int srow = l >> 2;
  const int scol = (l & 3) * 8;
  f32x4 acc[MI][4] = {};

  const int nk = K >> 5;
  for (int kt = 0; kt < nk; ++kt) {
    const int k0 = kt * 32;
#pragma unroll
    for (int j = 0; j < MI / 2; ++j) {
      const int grp = w * (MI / 2) + j;
      load_lds16(A + (size_t)(m0 + grp * 16 + srow) * K + k0 + scol, As + grp * 512);
    }
#pragma unroll
    for (int j = 0; j < 2; ++j) {
      const int grp = w * 2 + j;
      load_lds16(BT + (size_t)(n0 + grp * 16 + srow) * K + k0 + scol, Bs + grp * 512);
    }
    __syncthreads();
    short8v af[MI], bfr[4];
#pragma unroll
    for (int i = 0; i < MI; ++i)
      af[i] = *(const short8v*)&As[(wr * (16 * MI) + i * 16 + col) * 32 + hi * 8];
#pragma unroll
    for (int i = 0; i < 4; ++i)
      bfr[i] = *(const short8v*)&Bs[(wc * 64 + i * 16 + col) * 32 + hi * 8];
#pragma unroll
    for (int mi = 0; mi < MI; ++mi)
#pragma unroll
      for (int ni = 0; ni < 4; ++ni)
        acc[mi][ni] = __builtin_amdgcn_mfma_f32_16x16x32_bf16(af[mi], bfr[ni], acc[mi][ni], 0, 0, 0);
    __syncthreads();
  }

#pragma unroll
  for (int mi = 0; mi < MI; ++mi) {
#pragma unroll
    for (int ni = 0; ni < 4; ++ni) {
#pragma unroll
      for (int r = 0; r < 4; ++r) {
        const int m = m0 + wr * (16 * MI) + mi * 16 + hi * 4 + r;
        const int n = n0 + wc * 64 + ni * 16 + col;
        const float vv = acc[mi][ni][r] + bias[n];
        if (EPI == 0) {
          const int bb = m >> 11, ss = m & 2047;
          const int n1 = n - (zz << 10);
          const int hh = n1 >> 7, dd = n1 & 127;
          ((bf16*)outp)[(size_t)zz * 4194304 + (((size_t)bb * 8 + hh) * 2048 + ss) * 128 + dd] =
              __float2bfloat16(vv);
        } else if (EPI == 1) {
          const size_t idx = (size_t)m * N + n;
          ((float*)outp)[idx] = res[idx] + vv;
        } else {
          const size_t idx = (size_t)m * N + n;
          const float gg = 0.5f * vv * (1.0f + erff(vv * 0.70710678118f));
          ((bf16*)outp)[idx] = __float2bfloat16(gg);
        }
      }
    }
  }
}

// ---------------- causal flash attention v4: 8 waves, in-block KV split ----------------
// 256 blocks (pair {31-p, p}), 8 waves = 2 groups of 4.
// Group 0: KV tiles [0, ceil(T/2)); group 1: [ceil(T/2), T).  Each group has its own
// double-buffered K (XOR-swizzled via global_load_lds) and V^T buffers.
// Partial (m, l, o) merged through LDS at the end of each q-tile.
// LDS: K 4x16KB | V^T 4x18KB | Ps 8x2.25KB = 154 KB, 1 block/CU, 2 waves/SIMD.
__global__ __launch_bounds__(512) void attn_kernel(const bf16* __restrict__ q,
                                                   const bf16* __restrict__ k,
                                                   const bf16* __restrict__ v,
                                                   bf16* __restrict__ y) {
  __shared__ __align__(16) char lds_raw[157696];
  const int p = blockIdx.x;
  const int bh = blockIdx.y;
  const int tid = threadIdx.x;
  const int w = tid >> 6, l = tid & 63;
  const int grp = w >> 2, wg = w & 3;
  const int col = l & 15, hi = l >> 4;

  const bf16* kbase = k + (size_t)bh * 2048 * 128;
  const bf16* vbase = v + (size_t)bh * 2048 * 128;
  const int bb = bh >> 3, hh = bh & 7;

  bf16* Psw = (bf16*)(lds_raw + 139264 + (size_t)w * 2304);

  // staging lane mapping (within each 4-wave group)
  const int klr = (l >> 4);
  const int kblk0 = l & 15;
  const int vr = (l & 31) * 2;
  const int vcb = (wg * 2 + (l >> 5)) * 16;

  const float scale = 0.08838834764831845f;  // 1/sqrt(128)

  for (int half = 0; half < 2; ++half) {
    const int qt = half ? p : (31 - p);
    const int q0 = qt * 64;
    const int T = qt + 1;
    const int n0 = (T + 1) >> 1;
    const int myn = grp ? (T >> 1) : n0;
    const int tb = grp ? n0 : 0;

    // Q fragments: rows q0 + wg*16 + col (both groups load the same rows)
    short8v qf[4];
    const bf16* qp = q + ((size_t)bh * 2048 + q0 + wg * 16 + col) * 128;
#pragma unroll
    for (int c = 0; c < 4; ++c) qf[c] = *(const short8v*)(qp + c * 32 + hi * 8);

    f32x4 o[8] = {};
    float mx[4] = {-1e30f, -1e30f, -1e30f, -1e30f};
    float sm[4] = {0.f, 0.f, 0.f, 0.f};

    // ---- prologue: stage my group's tile tb into buf 0 ----
    if (myn > 0) {
      bf16* Ks0 = (bf16*)(lds_raw + (size_t)(grp * 2 + 0) * 16384);
      bf16* Vt0 = (bf16*)(lds_raw + 65536 + (size_t)(grp * 2 + 0) * 18432);
#pragma unroll
      for (int j = 0; j < 4; ++j) {
        const int lr = j * 4 + klr;
        const int blk = kblk0 ^ (lr & 7);
        load_lds16(kbase + (size_t)(tb * 64 + wg * 16 + lr) * 128 + blk * 8,
                   Ks0 + wg * 2048 + j * 512);
      }
      const bf16* vsrc = vbase + (size_t)(tb * 64 + vr) * 128 + vcb;
      short8v v00 = *(const short8v*)vsrc;
      short8v v01 = *(const short8v*)(vsrc + 8);
      short8v v10 = *(const short8v*)(vsrc + 128);
      short8v v11 = *(const short8v*)(vsrc + 136);
#pragma unroll
      for (int i = 0; i < 8; ++i) {
        *(unsigned int*)&Vt0[(vcb + i) * 72 + vr] =
            ((unsigned int)(unsigned short)v00[i]) | (((unsigned int)(unsigned short)v10[i]) << 16);
        *(unsigned int*)&Vt0[(vcb + 8 + i) * 72 + vr] =
            ((unsigned int)(unsigned short)v01[i]) | (((unsigned int)(unsigned short)v11[i]) << 16);
      }
    }
    __syncthreads();

    for (int it = 0; it < n0; ++it) {
      const int cur = it & 1;
      const bool active = it < myn;
      const bool havenext = (it + 1) < myn;
      bf16* KsCur = (bf16*)(lds_raw + (size_t)(grp * 2 + cur) * 16384);
      bf16* KsNxt = (bf16*)(lds_raw + (size_t)(grp * 2 + (cur ^ 1)) * 16384);
      bf16* VtCur = (bf16*)(lds_raw + 65536 + (size_t)(grp * 2 + cur) * 18432);
      bf16* VtNxt = (bf16*)(lds_raw + 65536 + (size_t)(grp * 2 + (cur ^ 1)) * 18432);

      // ---- issue next tile's loads early ----
      short8v v00, v01, v10, v11;
      if (havenext) {
        const int nt = tb + it + 1;
#pragma unroll
        for (int j = 0; j < 4; ++j) {
          const int lr = j * 4 + klr;
          const int blk = kblk0 ^ (lr & 7);
          load_lds16(kbase + (size_t)(nt * 64 + wg * 16 + lr) * 128 + blk * 8,
                     KsNxt + wg * 2048 + j * 512);
        }
        const bf16* vsrc = vbase + (size_t)(nt * 64 + vr) * 128 + vcb;
        v00 = *(const short8v*)vsrc;
        v01 = *(const short8v*)(vsrc + 8);
        v10 = *(const short8v*)(vsrc + 128);
        v11 = *(const short8v*)(vsrc + 136);
      }

      if (active) {
        const int ktile = tb + it;
        // ---- QK^T ----
        f32x4 s[4] = {};
        __builtin_amdgcn_s_setprio(1);
#pragma unroll
        for (int c = 0; c < 4; ++c) {
#pragma unroll
          for (int kg = 0; kg < 4; ++kg) {
            const int kr = kg * 16 + col;
            short8v kf = *(const short8v*)&KsCur[kr * 128 + ((c * 32 + hi * 8) ^ ((col & 7) << 3))];
            s[kg] = __builtin_amdgcn_mfma_f32_16x16x32_bf16(qf[c], kf, s[kg], 0, 0, 0);
          }
        }
        __builtin_amdgcn_s_setprio(0);

        // ---- online softmax ----
        const bool diag = (ktile == qt);
        const int qrl = wg * 16 + hi * 4;
        float al[4];
#pragma unroll
        for (int r = 0; r < 4; ++r) {
          float a0 = s[0][r] * scale, a1 = s[1][r] * scale;
          float a2 = s[2][r] * scale, a3 = s[3][r] * scale;
          if (diag) {
            const int qr = qrl + r;
            if (0 * 16 + col > qr) a0 = -1e30f;
            if (1 * 16 + col > qr) a1 = -1e30f;
            if (2 * 16 + col > qr) a2 = -1e30f;
            if (3 * 16 + col > qr) a3 = -1e30f;
          }
          float t = fmaxf(fmaxf(a0, a1), fmaxf(a2, a3));
#pragma unroll
          for (int mm = 1; mm < 16; mm <<= 1) t = fmaxf(t, __shfl_xor(t, mm));
          const float mn = fmaxf(mx[r], t);
          const float aa = __expf(mx[r] - mn);
          const float p0 = __expf(a0 - mn), p1 = __expf(a1 - mn);
          const float p2 = __expf(a2 - mn), p3 = __expf(a3 - mn);
          float ps = (p0 + p1) + (p2 + p3);
#pragma unroll
          for (int mm = 1; mm < 16; mm <<= 1) ps += __shfl_xor(ps, mm);
          sm[r] = sm[r] * aa + ps;
          mx[r] = mn; al[r] = aa;
          const int prow = (hi * 4 + r) * 72;
          Psw[prow + col]      = __float2bfloat16(p0);
          Psw[prow + col + 16] = __float2bfloat16(p1);
          Psw[prow + col + 32] = __float2bfloat16(p2);
          Psw[prow + col + 48] = __float2bfloat16(p3);
        }
#pragma unroll
        for (int db = 0; db < 8; ++db)
#pragma unroll
          for (int r = 0; r < 4; ++r) o[db][r] *= al[r];
      }

      // ---- write next V tile into other buffer ----
      if (havenext) {
#pragma unroll
        for (int i = 0; i < 8; ++i) {
          *(unsigned int*)&VtNxt[(vcb + i) * 72 + vr] =
              ((unsigned int)(unsigned short)v00[i]) | (((unsigned int)(unsigned short)v10[i]) << 16);
          *(unsigned int*)&VtNxt[(vcb + 8 + i) * 72 + vr] =
              ((unsigned int)(unsigned short)v01[i]) | (((unsigned int)(unsigned short)v11[i]) << 16);
        }
      }

      if (active) {
        // ---- PV: o += P @ V ----
        asm volatile("s_waitcnt lgkmcnt(0)" ::: "memory");
        __builtin_amdgcn_s_setprio(1);
#pragma unroll
        for (int ks = 0; ks < 2; ++ks) {
          short8v pf = *(const short8v*)&Psw[col * 72 + ks * 32 + hi * 8];
#pragma unroll
          for (int db = 0; db < 8; ++db) {
            short8v vf = *(const short8v*)&VtCur[(db * 16 + col) * 72 + ks * 32 + hi * 8];
            o[db] = __builtin_amdgcn_mfma_f32_16x16x32_bf16(pf, vf, o[db], 0, 0, 0);
          }
        }
        __builtin_amdgcn_s_setprio(0);
      }
      __syncthreads();
    }

    // ---- merge group partials through LDS (reuses K region) ----
    if (grp == 1) {
      float* Mo = (float*)(lds_raw + (size_t)wg * 8448);       // [16][132] fp32
      float* Ml = (float*)(lds_raw + 33792 + (size_t)wg * 128);// [16][2]
#pragma unroll
      for (int db = 0; db < 8; ++db)
#pragma unroll
        for (int r = 0; r < 4; ++r)
          Mo[(hi * 4 + r) * 132 + db * 16 + col] = o[db][r];
#pragma unroll
      for (int r = 0; r < 4; ++r) {
        Ml[(hi * 4 + r) * 2 + 0] = mx[r];
        Ml[(hi * 4 + r) * 2 + 1] = sm[r];
      }
    }
    __syncthreads();
    if (grp == 0) {
      const float* Mo = (const float*)(lds_raw + (size_t)wg * 8448);
      const float* Ml = (const float*)(lds_raw + 33792 + (size_t)wg * 128);
      float a0[4], a1[4], inv[4];
#pragma unroll
      for (int r = 0; r < 4; ++r) {
        const float m1 = Ml[(hi * 4 + r) * 2 + 0];
        const float l1 = Ml[(hi * 4 + r) * 2 + 1];
        const float M = fmaxf(mx[r], m1);
        a0[r] = __expf(mx[r] - M);
        a1[r] = __expf(m1 - M);
        inv[r] = 1.0f / (sm[r] * a0[r] + l1 * a1[r]);
      }
#pragma unroll
      for (int db = 0; db < 8; ++db) {
#pragma unroll
        for (int r = 0; r < 4; ++r) {
          const float oc = o[db][r] * a0[r] + Mo[(hi * 4 + r) * 132 + db * 16 + col] * a1[r];
          const int qg = q0 + wg * 16 + hi * 4 + r;
          y[((size_t)bb * 2048 + qg) * 1024 + hh * 128 + db * 16 + col] =
              __float2bfloat16(oc * inv[r]);
        }
      }
    }
    __syncthreads();
  }
}

extern "C" void kernel_launch(void* const* d_in, const int* in_sizes, int n_in,
                              void* d_out, int out_size, void* d_ws, size_t ws_size,
                              hipStream_t stream) {
  const float* x    = (const float*)d_in[0];
  const float* ln1g = (const float*)d_in[1];
  const float* ln1b = (const float*)d_in[2];
  const float* ln2g = (const float*)d_in[3];
  const float* ln2b = (const float*)d_in[4];
  const float* Wq   = (const float*)d_in[5];
  const float* bq   = (const float*)d_in[6];
  const float* Wk   = (const float*)d_in[7];
  const float* bk   = (const float*)d_in[8];
  const float* Wv   = (const float*)d_in[9];
  const float* bv   = (const float*)d_in[10];
  const float* Wo   = (const float*)d_in[11];
  const float* bo   = (const float*)d_in[12];
  const float* W1   = (const float*)d_in[13];
  const float* b1   = (const float*)d_in[14];
  const float* W2   = (const float*)d_in[15];
  const float* b2   = (const float*)d_in[16];
  float* out = (float*)d_out;
  char* ws = (char*)d_ws;
  const size_t MB = 1024 * 1024;

  bf16* WqT = (bf16*)(ws + 0 * MB);   // [3072][1024] merged qkv starts here
  bf16* WkT = (bf16*)(ws + 2 * MB);
  bf16* WvT = (bf16*)(ws + 4 * MB);
  bf16* WoT = (bf16*)(ws + 6 * MB);
  bf16* W1T = (bf16*)(ws + 8 * MB);   // [4096][1024]
  bf16* W2T = (bf16*)(ws + 16 * MB);  // [1024][4096]
  bf16* h   = (bf16*)(ws + 24 * MB);
  bf16* qb  = (bf16*)(ws + 32 * MB);  // qkv base: q,k,v contiguous 8MB each
  bf16* kb  = (bf16*)(ws + 40 * MB);
  bf16* vb  = (bf16*)(ws + 48 * MB);
  bf16* y   = (bf16*)(ws + 56 * MB);
  bf16* g   = (bf16*)(ws + 32 * MB);
  float* x1 = (float*)(ws + 64 * MB);
  bf16* h2  = h;

  tconv_all<<<3072, 256, 0, stream>>>(Wq, Wk, Wv, Wo, W1, W2, WqT, WkT, WvT, WoT, W1T, W2T);

  ln_kernel<<<4096, 256, 0, stream>>>(x, ln1g, ln1b, h);

  gemm128<0, 4><<<dim3(24, 32), 256, 0, stream>>>(h, WqT, bq, bk, bv, nullptr, qb,
                                                  4096, 3072, 1024);

  attn_kernel<<<dim3(16, 16), 512, 0, stream>>>(qb, kb, vb, y);

  gemm128<1, 2><<<dim3(8, 64), 256, 0, stream>>>(y, WoT, bo, nullptr, nullptr, x, x1,
                                                 4096, 1024, 1024);

  ln_kernel<<<4096, 256, 0, stream>>>(x1, ln2g, ln2b, h2);

  gemm128<2, 4><<<dim3(32, 32), 256, 0, stream>>>(h2, W1T, b1, nullptr, nullptr, nullptr, g,
                                                  4096, 4096, 1024);

  gemm128<1, 2><<<dim3(8, 64), 256, 0, stream>>>(g, W2T, b2, nullptr, nullptr, x1, out,
                                                 4096, 1024, 4096);
}